// Round 13
// baseline (942.585 us; speedup 1.0000x reference)
//
#include <hip/hip_runtime.h>
#include <math.h>

#define H0 120
#define W0 120
#define H1 240
#define W1 240
#define L  14400   // 120*120
#define FDIM 144   // 16*9
#define CPAD 160   // FDIM padded to 5*32
#define LPAD 14464 // keys padded to 904*16 (dups of key L-1)

#define KC     128      // keys per staging chunk in k_simh
#define NCHT   113      // staging chunks = LPAD/KC
#define NCHB   8        // chunks per block (grid.y = 15)
#define NGRAN  904      // flag granules (16 keys each) = LPAD/16
#define NLIST  32       // flagged-granule list cap (overflow -> fallback scan)
#define MARGIN 6.5e-3f  // >= 2*E_f16 (2*2^-11 CS + subnormal flush) + f16 storage bias

typedef _Float16 half8 __attribute__((ext_vector_type(8)));
typedef float    f32x4 __attribute__((ext_vector_type(4)));

__device__ __forceinline__ double meanc(int c){ return c==0?0.485:(c==1?0.456:0.406); }
__device__ __forceinline__ double stdc (int c){ return c==0?0.229:(c==1?0.224:0.225); }

// ---------------- all weights f32 -> f64 in one launch
__global__ __launch_bounds__(256) void k_cvt_all(const float* __restrict__ w1, const float* __restrict__ b1,
                                                 const float* __restrict__ w2, const float* __restrict__ b2,
                                                 const float* __restrict__ w3, const float* __restrict__ b3,
                                                 const float* __restrict__ wm, const float* __restrict__ bm,
                                                 double* __restrict__ wd){
  int i = blockIdx.x*256 + threadIdx.x;
  if (i >= 114640) return;
  float v;
  if      (i < 1728)   v = w1[i];
  else if (i < 1792)   v = b1[i-1728];
  else if (i < 38656)  v = w2[i-1792];
  else if (i < 38720)  v = b2[i-38656];
  else if (i < 112448) v = w3[i-38720];
  else if (i < 112576) v = b3[i-112448];
  else if (i < 114624) v = wm[i-112576];
  else                 v = bm[i-114624];
  wd[i] = (double)v;
}

// ---------------- prep: nq[2][3][120][120]  (b=0: norm(query); b=1: norm(avgpool2(key)))
__global__ __launch_bounds__(256) void k_prep(const float* __restrict__ query,
                                              const float* __restrict__ key,
                                              float* __restrict__ nq){
  int i = blockIdx.x*256 + threadIdx.x;
  if (i >= 2*3*L) return;
  int b = i/(3*L); int r = i - b*3*L; int c = r / L; int p = r - c*L;
  double v;
  if (b==0){
    v = (double)query[c*L + p];
  } else {
    int y = p / W0, x = p - y*W0;
    const float* kk = key + (size_t)c*(H1*W1);
    int yy = 2*y, xx = 2*x;
    v = 0.25*((double)kk[yy*W1+xx] + (double)kk[yy*W1+xx+1]
            + (double)kk[(yy+1)*W1+xx] + (double)kk[(yy+1)*W1+xx+1]);
  }
  nq[i] = (float)((v - meanc(c)) / stdc(c));
}

// cubic kernel, a = -0.75 (torch bicubic), double
__device__ __forceinline__ double cubw(double x){
  x = fabs(x);
  if (x <= 1.0)      return (1.25*x - 2.25)*x*x + 1.0;
  else if (x < 2.0)  return -0.75*(((x - 5.0)*x + 8.0)*x - 4.0);
  return 0.0;
}

// ---------------- bicubic x2 upsample, align_corners=True: up[2][3][240][240] <- nq
__global__ __launch_bounds__(256) void k_bicubic(const float* __restrict__ nq,
                                                 float* __restrict__ up){
  int i = blockIdx.x*256 + threadIdx.x;
  if (i >= 2*3*H1*W1) return;
  int bc = i/(H1*W1); int r = i - bc*H1*W1; int oy = r/W1, ox = r - oy*W1;
  double sy = (double)oy * (double)(H0-1) / (double)(H1-1);
  double sx = (double)ox * (double)(W0-1) / (double)(W1-1);
  int fy = (int)floor(sy); double ty = sy - (double)fy;
  int fx = (int)floor(sx); double tx = sx - (double)fx;
  double wy[4], wx[4]; int iy[4], ix[4];
  #pragma unroll
  for (int o=0;o<4;++o){
    wy[o] = cubw(ty - (double)(o-1));
    wx[o] = cubw(tx - (double)(o-1));
    int yv = fy + o - 1; iy[o] = min(max(yv,0),H0-1);
    int xv = fx + o - 1; ix[o] = min(max(xv,0),W0-1);
  }
  const float* src = nq + (size_t)bc*(H0*W0);
  double acc = 0.0;
  #pragma unroll
  for (int j=0;j<4;++j){
    double colv = 0.0;
    #pragma unroll
    for (int a=0;a<4;++a) colv += wy[a]*(double)src[iy[a]*W0 + ix[j]];
    acc += wx[j]*colv;
  }
  up[i] = (float)acc;
}

// ---------------- 3x3 conv, pad 1, ReLU, fp64 accumulation.
// 30x30 tile, thread = 2x2 px * 8 oc. Register-staged DOUBLE-BUFFERED LDS:
// issue chunk k+1 global loads -> compute chunk k -> write regs to other buf ->
// one barrier per chunk (global latency hides under compute, no phase stall).
// Accumulation order (ci ascending, taps ky-major ascending) identical to
// previous rounds -> bit-identical output.
template<int CIN, int CIC, int HW>
__global__ __launch_bounds__(256, 4) void k_conv3x3(const float* __restrict__ in,
                                                    const double* __restrict__ w,
                                                    const double* __restrict__ bias,
                                                    float* __restrict__ out, int CO){
  constexpr int T = 30, TI = 32, TP = 36;   // TP*4B = 144B, 16B-aligned rows
  constexpr int NT = HW / T;
  constexpr int NCH = CIN / CIC;
  __shared__ __align__(16) float s_in[2][CIC][TI][TP];
  int tid = threadIdx.x;
  int tile = blockIdx.x; int trow = tile/NT;
  int ty0 = trow*T, tx0 = (tile - trow*NT)*T;
  int ocb = blockIdx.y*8; int b = blockIdx.z;
  const float* inb = in + (size_t)b*CIN*HW*HW;
  bool active = tid < 225;
  int tyy = (tid/15)*2, txx = (tid%15)*2;
  // staging coords (all 256 threads): granule (rr, c4) fixed per thread, ci = j
  int srr = tid >> 3, sc4 = tid & 7;
  int sgy = ty0 + srr - 1, sgx0 = tx0 + sc4*4 - 1;
  bool interior = (ty0 > 0) && (ty0 + TI - 1 <= HW) && (tx0 > 0) && (tx0 + TI - 1 <= HW);

  double acc[2][2][8];
  #pragma unroll
  for (int o=0;o<8;++o){
    double bv = bias[ocb+o];
    acc[0][0][o]=bv; acc[0][1][o]=bv; acc[1][0][o]=bv; acc[1][1][o]=bv;
  }

  float4 regs[CIC];
  auto gload = [&](int c0){
    if (interior){
      #pragma unroll
      for (int j=0;j<CIC;++j)
        regs[j] = *(const float4*)(inb + (size_t)(c0+j)*HW*HW + (size_t)sgy*HW + sgx0);
    } else {
      #pragma unroll
      for (int j=0;j<CIC;++j){
        float4 v = {0.f,0.f,0.f,0.f};
        if (sgy >= 0 && sgy < HW){
          const float* rowp = inb + (size_t)(c0+j)*HW*HW + (size_t)sgy*HW;
          float* vp = (float*)&v;
          #pragma unroll
          for (int e=0;e<4;++e){
            int gx = sgx0 + e;
            if (gx >= 0 && gx < HW) vp[e] = rowp[gx];
          }
        }
        regs[j] = v;
      }
    }
  };
  auto swrite = [&](int buf){
    #pragma unroll
    for (int j=0;j<CIC;++j)
      *(float4*)&s_in[buf][j][srr][sc4*4] = regs[j];
  };

  gload(0);
  swrite(0);
  __syncthreads();
  for (int k=0; k<NCH; ++k){
    int cur = k & 1;
    if (k+1 < NCH) gload((k+1)*CIC);       // prefetch next chunk (latency hidden)
    if (active){
      #pragma unroll
      for (int ci=0; ci<CIC; ++ci){
        const double* wp = w + ((size_t)ocb*CIN + (k*CIC+ci))*9;
        // rolling 2-row tap window (rows tyy+ky, tyy+ky+1)
        double r0[4], r1[4];
        {
          float2 lo = *(const float2*)&s_in[cur][ci][tyy+0][txx];
          float2 hi = *(const float2*)&s_in[cur][ci][tyy+0][txx+2];
          r0[0]=(double)lo.x; r0[1]=(double)lo.y; r0[2]=(double)hi.x; r0[3]=(double)hi.y;
          lo = *(const float2*)&s_in[cur][ci][tyy+1][txx];
          hi = *(const float2*)&s_in[cur][ci][tyy+1][txx+2];
          r1[0]=(double)lo.x; r1[1]=(double)lo.y; r1[2]=(double)hi.x; r1[3]=(double)hi.y;
        }
        #pragma unroll
        for (int ky=0; ky<3; ++ky){
          #pragma unroll
          for (int kx=0; kx<3; ++kx){
            #pragma unroll
            for (int o=0;o<8;++o){
              double wv = wp[(size_t)o*CIN*9 + ky*3 + kx];   // block-uniform -> s_load
              acc[0][0][o] += r0[kx+0]*wv;
              acc[0][1][o] += r0[kx+1]*wv;
              acc[1][0][o] += r1[kx+0]*wv;
              acc[1][1][o] += r1[kx+1]*wv;
            }
          }
          if (ky < 2){
            #pragma unroll
            for (int e=0;e<4;++e) r0[e] = r1[e];
            float2 lo = *(const float2*)&s_in[cur][ci][tyy+ky+2][txx];
            float2 hi = *(const float2*)&s_in[cur][ci][tyy+ky+2][txx+2];
            r1[0]=(double)lo.x; r1[1]=(double)lo.y; r1[2]=(double)hi.x; r1[3]=(double)hi.y;
          }
        }
      }
    }
    if (k+1 < NCH){
      swrite(cur ^ 1);                      // write next chunk to other buffer
      __syncthreads();                      // one barrier per chunk
    }
  }

  if (active){
    #pragma unroll
    for (int py=0;py<2;++py)
      #pragma unroll
      for (int px=0;px<2;++px){
        int gy = ty0+tyy+py, gx = tx0+txx+px;
        float* op = out + ((size_t)(b*CO+ocb)*HW + gy)*HW + gx;
        #pragma unroll
        for (int o=0;o<8;++o){
          double v = acc[py][px][o];
          op[(size_t)o*HW*HW] = (float)(v>0.0 ? v : 0.0);
        }
      }
  }
}

// ---------------- 2x2 max pool: (2,64,240,240) -> (2,64,120,120)  (exact)
__global__ __launch_bounds__(256) void k_maxpool(const float* __restrict__ in,
                                                 float* __restrict__ out){
  int i = blockIdx.x*256 + threadIdx.x;
  if (i >= 2*64*L) return;
  int bc = i / L; int p = i - bc*L; int y = p/W0, x = p - y*W0;
  const float* s = in + (size_t)bc*H1*W1;
  int yy = 2*y, xx = 2*x;
  out[i] = fmaxf(fmaxf(s[yy*W1+xx], s[yy*W1+xx+1]),
                 fmaxf(s[(yy+1)*W1+xx], s[(yy+1)*W1+xx+1]));
}

// ---------------- 1x1 conv 128->16 + LeakyReLU(0.2), fp64 accumulation
__global__ __launch_bounds__(256) void k_conv1x1(const float* __restrict__ in,
                                                 const double* __restrict__ wm,
                                                 const double* __restrict__ bm,
                                                 float* __restrict__ out){
  int i = blockIdx.x*256 + threadIdx.x;
  if (i >= 2*L) return;
  int b = i/L; int p = i - b*L;
  double a[16];
  #pragma unroll
  for (int o=0;o<16;++o) a[o] = bm[o];
  const float* src = in + (size_t)b*128*L + p;
  for (int ci=0; ci<128; ++ci){
    double v = (double)src[(size_t)ci*L];
    #pragma unroll
    for (int o=0;o<16;++o) a[o] += v * wm[o*128 + ci];  // uniform -> scalar load
  }
  float* dst = out + (size_t)b*16*L + p;
  #pragma unroll
  for (int o=0;o<16;++o){ double v=a[o]; dst[(size_t)o*L] = (float)(v>0.0 ? v : 0.2*v); }
}

// ---------------- im2col 3x3 pad1 + per-pixel L2 normalize (fp64), pixel-major outputs
__global__ __launch_bounds__(256) void k_patches(const float* __restrict__ fm,
                                                 _Float16* __restrict__ Tq16,
                                                 _Float16* __restrict__ Tk16,
                                                 float* __restrict__ Tq32,
                                                 float* __restrict__ Tk32){
  int i = blockIdx.x*256 + threadIdx.x;
  if (i >= 2*L + (LPAD - L)) return;
  int b, p, row;
  if (i < 2*L){ b = i / L; p = i - b*L; row = p; }
  else        { b = 1; p = L - 1; row = L + (i - 2*L); }
  int y = p/W0, x = p - y*W0;
  const float* src = fm + (size_t)b*16*L;
  double ss = 0.0;
  for (int c=0;c<16;++c){
    #pragma unroll
    for (int dy=0;dy<3;++dy){
      int gy = y+dy-1;
      #pragma unroll
      for (int dx=0;dx<3;++dx){
        int gx = x+dx-1;
        double v = (gy>=0 && gy<H0 && gx>=0 && gx<W0) ? (double)src[c*L + gy*W0 + gx] : 0.0;
        ss += v*v;
      }
    }
  }
  double rn = 1.0 / fmax(sqrt(ss), 1e-12);
  _Float16* d16 = (b==0 ? Tq16 : Tk16) + (size_t)row*CPAD;
  float*    d32 = (b==0 ? Tq32 : Tk32) + (size_t)row*CPAD;
  for (int c=0;c<16;++c){
    #pragma unroll
    for (int dy=0;dy<3;++dy){
      int gy = y+dy-1;
      #pragma unroll
      for (int dx=0;dx<3;++dx){
        int gx = x+dx-1;
        double v = (gy>=0 && gy<H0 && gx>=0 && gx<W0) ? (double)src[c*L + gy*W0 + gx] : 0.0;
        float f = (float)(v*rn);
        int idx = c*9 + dy*3 + dx;
        d32[idx] = f;
        d16[idx] = (_Float16)f;
      }
    }
  }
  for (int c=FDIM;c<CPAD;++c){ d32[c] = 0.f; d16[c] = (_Float16)0.f; }
}

// ---------------- PASS 1: f16 MFMA similarity scan -> per-(16-key-granule,query) max
__global__ __launch_bounds__(256) void k_simh(const _Float16* __restrict__ Tq,
                                              const _Float16* __restrict__ Tk,
                                              _Float16* __restrict__ cmaxh){
  __shared__ __align__(16) _Float16 skT[40*512];   // [kg 0..7][ks 0..4][cg][kk][8] = 40 KB
  int tid = threadIdx.x;
  int wid = tid >> 6, lane = tid & 63;
  int wk = wid & 1, wq = wid >> 1;
  int q0 = blockIdx.x * 96;
  int cg = lane >> 4;
  int qb = q0 + wq*48 + (lane & 15);
  half8 fB[3][5];
  #pragma unroll
  for (int bf=0; bf<3; ++bf)
    #pragma unroll
    for (int ks=0; ks<5; ++ks)
      fB[bf][ks] = *(const half8*)(Tq + (size_t)(qb + bf*16)*CPAD + ks*32 + cg*8);
  int ch0 = blockIdx.y * NCHB;
  for (int cc=0; cc<NCHB; ++cc){
    int chunk = ch0 + cc;
    if (chunk >= NCHT) break;
    int kbase = chunk * KC;
    __syncthreads();            // prior chunk's skT reads done
    #pragma unroll
    for (int it=0; it<10; ++it){
      int b1 = wid*10 + it;     // 1024-B block: kg=b1/5, ks=b1%5
      int kg = b1 / 5, ks = b1 % 5;
      const _Float16* g = Tk + (size_t)(kbase + kg*16 + (lane&15))*CPAD + ks*32 + cg*8;
      __builtin_amdgcn_global_load_lds((const __attribute__((address_space(1))) void*)g,
                                       (__attribute__((address_space(3))) void*)(skT + b1*512),
                                       16, 0, 0);
    }
    __syncthreads();            // staging complete
    f32x4 acc[4][3];
    #pragma unroll
    for (int kf=0;kf<4;++kf)
      #pragma unroll
      for (int bf=0;bf<3;++bf)
        acc[kf][bf] = (f32x4){0.f,0.f,0.f,0.f};
    #pragma unroll
    for (int ks=0; ks<5; ++ks){
      #pragma unroll
      for (int kf=0; kf<4; ++kf){
        half8 av = *(const half8*)(skT + ((size_t)((wk*4+kf)*5 + ks))*512 + lane*8);
        #pragma unroll
        for (int bf=0; bf<3; ++bf)
          acc[kf][bf] = __builtin_amdgcn_mfma_f32_16x16x32_f16(av, fB[bf][ks], acc[kf][bf], 0, 0, 0);
      }
    }
    // per-(16-key granule, query) max, biased-up f16 store
    #pragma unroll
    for (int kf=0; kf<4; ++kf){
      int gran = chunk*8 + wk*4 + kf;
      #pragma unroll
      for (int bf=0; bf<3; ++bf){
        f32x4 a = acc[kf][bf];
        float m = fmaxf(fmaxf(a.x, a.y), fmaxf(a.z, a.w));
        m = fmaxf(m, __shfl_xor(m, 16));
        m = fmaxf(m, __shfl_xor(m, 32));
        float mb = m * (m >= 0.f ? 1.0009765625f : 0.9990234375f);  // round-up bias
        if (lane < 16)
          cmaxh[(size_t)gran*L + q0 + wq*48 + bf*16 + lane] = (_Float16)mb;
      }
    }
  }
}

// ---------------- PASS 2a: wave-per-query gmax + ascending flagged list.
__global__ __launch_bounds__(256) void k_flag(const _Float16* __restrict__ cmaxh,
                                              unsigned short* __restrict__ list,
                                              int* __restrict__ nf,
                                              float* __restrict__ thrv){
  int q    = blockIdx.x*4 + (threadIdx.x >> 6);
  int lane = threadIdx.x & 63;
  if (q >= L) return;
  float v[15];
  #pragma unroll
  for (int j=0;j<15;++j){
    int g = j*64 + lane;
    v[j] = (g < NGRAN) ? (float)cmaxh[(size_t)g*L + q] : -1e30f;
  }
  float m = -1e30f;
  #pragma unroll
  for (int j=0;j<15;++j) m = fmaxf(m, v[j]);
  #pragma unroll
  for (int d=32; d>=1; d>>=1) m = fmaxf(m, __shfl_xor(m, d));
  float thr = m - MARGIN;
  unsigned short* lst = list + (size_t)q*NLIST;
  int base = 0;
  #pragma unroll
  for (int j=0;j<15;++j){
    bool f = v[j] >= thr;
    unsigned long long mask = __ballot(f);
    if (f){
      int pos = base + __popcll(mask & ((1ull<<lane)-1ull));
      if (pos < NLIST) lst[pos] = (unsigned short)(j*64 + lane);
    }
    base += __popcll(mask);
  }
  if (lane == 0){ nf[q] = base; thrv[q] = thr; }
}

// ---------------- PASS 2b: fp64 rescore of flagged granules, one wave per query.
__global__ __launch_bounds__(64) void k_rescore3(const float* __restrict__ Tq32,
                                                 const float* __restrict__ Tk32,
                                                 const unsigned short* __restrict__ list,
                                                 const int* __restrict__ nf,
                                                 const float* __restrict__ thrv,
                                                 const _Float16* __restrict__ cmaxh,
                                                 float* __restrict__ out){
  int q = blockIdx.x, lane = threadIdx.x;
  int slot = lane & 15, quarter = lane >> 4;
  const float* qp = Tq32 + (size_t)q*CPAD + quarter*36;
  double q64[36];
  #pragma unroll
  for (int c=0;c<36;++c) q64[c] = (double)qp[c];
  int n = nf[q];
  float thr = thrv[q];
  double best = -1e300; int bi = 0x7fffffff;

  auto proc = [&](int g){
    int key = g*16 + slot;                    // key < LPAD always
    const float* kr = Tk32 + (size_t)key*CPAD + quarter*36;
    double s = 0.0;
    #pragma unroll
    for (int c=0;c<36;++c) s += q64[c]*(double)kr[c];
    s += __shfl_xor(s, 16);
    s += __shfl_xor(s, 32);                   // full dot for this slot's key, all lanes
    if (key < L && s > best){ best = s; bi = key; }  // dup keys (>=L) excluded
  };

  if (n <= NLIST){
    const unsigned short* lst = list + (size_t)q*NLIST;
    for (int it=0; it<n; ++it) proc(lst[it]);
  } else {
    for (int g=0; g<NGRAN; ++g)               // rare fallback (mass ties)
      if ((float)cmaxh[(size_t)g*L + q] >= thr) proc(g);
  }
  // cross-slot reduce with min-index tie-break (quarter lanes mirror slot state)
  #pragma unroll
  for (int d=1; d<16; d<<=1){
    double v2 = __shfl_xor(best, d);
    int    i2 = __shfl_xor(bi, d);
    if (v2 > best || (v2 == best && i2 < bi)){ best = v2; bi = i2; }
  }
  if (lane == 0){
    out[q]     = (float)best;     // rel
    out[L + q] = (float)bi;       // idx (exact in f32: < 2^24)
  }
}

extern "C" void kernel_launch(void* const* d_in, const int* in_sizes, int n_in,
                              void* d_out, int out_size, void* d_ws, size_t ws_size,
                              hipStream_t stream){
  const float* query = (const float*)d_in[0];
  const float* key   = (const float*)d_in[1];
  const float* w1 = (const float*)d_in[2];
  const float* b1 = (const float*)d_in[3];
  const float* w2 = (const float*)d_in[4];
  const float* b2 = (const float*)d_in[5];
  const float* w3 = (const float*)d_in[6];
  const float* b3 = (const float*)d_in[7];
  const float* wm = (const float*)d_in[8];
  const float* bm = (const float*)d_in[9];
  float* out = (float*)d_out;

  // ---- workspace layout ----
  double* wd = (double*)d_ws;   // 114640 doubles of converted weights
  double* wd1 = wd;            // 1728
  double* bd1 = wd + 1728;     // 64
  double* wd2 = wd + 1792;     // 36864
  double* bd2 = wd + 38656;    // 64
  double* wd3 = wd + 38720;    // 73728
  double* bd3 = wd + 112448;   // 128
  double* wdm = wd + 112576;   // 2048
  double* bdm = wd + 114624;   // 16
  float* fbase = (float*)d_ws + 230400;
  float* nq = fbase;                            //   86400
  float* up = nq + 86400;                       //  345600
  float* A  = up + 345600;                      // 7372800  (conv1 out)
  float* Bf = A  + 7372800;                     // 7372800  (conv2 out)
  float* C  = A;                                // 1843200  (pool out; A dead after conv2)
  float* D  = A + 1843200;                      // 3686400  (conv3 out)
  float* FM = Bf + 7372800 - 460800;            //  460800  (1x1 out; Bf tail = A+14,284,800)
  // pixel-major sim operands overlay A/Bf-head (dead by k_patches time):
  _Float16* Tq16 = (_Float16*)A;                          // 2,304,000 h = 1,152,000 fl
  _Float16* Tk16 = (_Float16*)(A + 1152000);              // 2,314,240 h = 1,157,120 fl
  float*    Tq32 = A + 2309120;                           // 2,304,000 fl
  float*    Tk32 = Tq32 + 2304000;                        // 2,314,240 fl (ends A+6,927,360)
  _Float16* cmaxh = (_Float16*)(A + 6927360);             // 904*14400 h = 6,508,800 fl
  unsigned short* list = (unsigned short*)(A + 13436160); // 14400*32 u16 = 230,400 fl
  int*   nfl  = (int*)(A + 13666560);                     // 14,400 fl
  float* thrv = A + 13680960;                             // 14,400 fl (ends A+13,695,360 < FM)

  k_cvt_all<<<(114640+255)/256, 256, 0, stream>>>(w1,b1,w2,b2,w3,b3,wm,bm, wd);

  k_prep   <<<(2*3*L + 255)/256, 256, 0, stream>>>(query, key, nq);
  k_bicubic<<<(2*3*H1*W1 + 255)/256, 256, 0, stream>>>(nq, up);
  k_conv3x3<3,3,240><<<dim3(64,8,2), 256, 0, stream>>>(up, wd1, bd1, A, 64);
  k_conv3x3<64,4,240><<<dim3(64,8,2), 256, 0, stream>>>(A, wd2, bd2, Bf, 64);
  k_maxpool<<<(2*64*L + 255)/256, 256, 0, stream>>>(Bf, C);
  k_conv3x3<64,4,120><<<dim3(16,16,2), 256, 0, stream>>>(C, wd3, bd3, D, 128);
  k_conv1x1<<<(2*L + 255)/256, 256, 0, stream>>>(D, wdm, bdm, FM);
  k_patches<<<(2*L + (LPAD-L) + 255)/256, 256, 0, stream>>>(FM, Tq16, Tk16, Tq32, Tk32);
  k_simh   <<<dim3(150, 15), 256, 0, stream>>>(Tq16, Tk16, cmaxh);
  k_flag   <<<(L + 3)/4, 256, 0, stream>>>(cmaxh, list, nfl, thrv);
  k_rescore3<<<L, 64, 0, stream>>>(Tq32, Tk32, list, nfl, thrv, cmaxh, out);
}

// Round 14
// 642.157 us; speedup vs baseline: 1.4678x; 1.4678x over previous
//
#include <hip/hip_runtime.h>
#include <math.h>

#define H0 120
#define W0 120
#define H1 240
#define W1 240
#define L  14400   // 120*120
#define FDIM 144   // 16*9
#define CPAD 160   // FDIM padded to 5*32
#define LPAD 14464 // keys padded to 904*16 (dups of key L-1)

#define KC     128      // keys per staging chunk in k_simh
#define NCHT   113      // staging chunks = LPAD/KC
#define NCHB   8        // chunks per block (grid.y = 15)
#define NGRAN  904      // flag granules (16 keys each) = LPAD/16
#define NLIST  32       // flagged-granule list cap (overflow -> fallback scan)
#define MARGIN 6.5e-3f  // >= 2*E_f16 (2*2^-11 CS + subnormal flush) + f16 storage bias

typedef _Float16 half8 __attribute__((ext_vector_type(8)));
typedef float    f32x4 __attribute__((ext_vector_type(4)));

__device__ __forceinline__ double meanc(int c){ return c==0?0.485:(c==1?0.456:0.406); }
__device__ __forceinline__ double stdc (int c){ return c==0?0.229:(c==1?0.224:0.225); }

// ---------------- all weights f32 -> f64 in one launch
__global__ __launch_bounds__(256) void k_cvt_all(const float* __restrict__ w1, const float* __restrict__ b1,
                                                 const float* __restrict__ w2, const float* __restrict__ b2,
                                                 const float* __restrict__ w3, const float* __restrict__ b3,
                                                 const float* __restrict__ wm, const float* __restrict__ bm,
                                                 double* __restrict__ wd){
  int i = blockIdx.x*256 + threadIdx.x;
  if (i >= 114640) return;
  float v;
  if      (i < 1728)   v = w1[i];
  else if (i < 1792)   v = b1[i-1728];
  else if (i < 38656)  v = w2[i-1792];
  else if (i < 38720)  v = b2[i-38656];
  else if (i < 112448) v = w3[i-38720];
  else if (i < 112576) v = b3[i-112448];
  else if (i < 114624) v = wm[i-112576];
  else                 v = bm[i-114624];
  wd[i] = (double)v;
}

// ---------------- prep: nq[2][3][120][120]  (b=0: norm(query); b=1: norm(avgpool2(key)))
__global__ __launch_bounds__(256) void k_prep(const float* __restrict__ query,
                                              const float* __restrict__ key,
                                              float* __restrict__ nq){
  int i = blockIdx.x*256 + threadIdx.x;
  if (i >= 2*3*L) return;
  int b = i/(3*L); int r = i - b*3*L; int c = r / L; int p = r - c*L;
  double v;
  if (b==0){
    v = (double)query[c*L + p];
  } else {
    int y = p / W0, x = p - y*W0;
    const float* kk = key + (size_t)c*(H1*W1);
    int yy = 2*y, xx = 2*x;
    v = 0.25*((double)kk[yy*W1+xx] + (double)kk[yy*W1+xx+1]
            + (double)kk[(yy+1)*W1+xx] + (double)kk[(yy+1)*W1+xx+1]);
  }
  nq[i] = (float)((v - meanc(c)) / stdc(c));
}

// cubic kernel, a = -0.75 (torch bicubic), double
__device__ __forceinline__ double cubw(double x){
  x = fabs(x);
  if (x <= 1.0)      return (1.25*x - 2.25)*x*x + 1.0;
  else if (x < 2.0)  return -0.75*(((x - 5.0)*x + 8.0)*x - 4.0);
  return 0.0;
}

// ---------------- bicubic x2 upsample, align_corners=True: up[2][3][240][240] <- nq
__global__ __launch_bounds__(256) void k_bicubic(const float* __restrict__ nq,
                                                 float* __restrict__ up){
  int i = blockIdx.x*256 + threadIdx.x;
  if (i >= 2*3*H1*W1) return;
  int bc = i/(H1*W1); int r = i - bc*H1*W1; int oy = r/W1, ox = r - oy*W1;
  double sy = (double)oy * (double)(H0-1) / (double)(H1-1);
  double sx = (double)ox * (double)(W0-1) / (double)(W1-1);
  int fy = (int)floor(sy); double ty = sy - (double)fy;
  int fx = (int)floor(sx); double tx = sx - (double)fx;
  double wy[4], wx[4]; int iy[4], ix[4];
  #pragma unroll
  for (int o=0;o<4;++o){
    wy[o] = cubw(ty - (double)(o-1));
    wx[o] = cubw(tx - (double)(o-1));
    int yv = fy + o - 1; iy[o] = min(max(yv,0),H0-1);
    int xv = fx + o - 1; ix[o] = min(max(xv,0),W0-1);
  }
  const float* src = nq + (size_t)bc*(H0*W0);
  double acc = 0.0;
  #pragma unroll
  for (int j=0;j<4;++j){
    double colv = 0.0;
    #pragma unroll
    for (int a=0;a<4;++a) colv += wy[a]*(double)src[iy[a]*W0 + ix[j]];
    acc += wx[j]*colv;
  }
  up[i] = (float)acc;
}

// ---------------- 3x3 conv, pad 1, ReLU, fp64 accumulation. (round-12 structure,
// best measured: CIC=8 single-buffer, TP=36 aligned b64 taps, 2 barriers/chunk)
template<int CIN, int CIC, int HW>
__global__ __launch_bounds__(256) void k_conv3x3(const float* __restrict__ in,
                                                 const double* __restrict__ w,
                                                 const double* __restrict__ bias,
                                                 float* __restrict__ out, int CO){
  constexpr int T = 30, TI = 32, TP = 36;
  constexpr int NT = HW / T;
  __shared__ __align__(16) float s_in[CIC][TI][TP];
  int tid = threadIdx.x;
  int tile = blockIdx.x; int trow = tile/NT;
  int ty0 = trow*T, tx0 = (tile - trow*NT)*T;
  int ocb = blockIdx.y*8; int b = blockIdx.z;
  const float* inb = in + (size_t)b*CIN*HW*HW;
  bool active = tid < 225;
  int tyy = (tid/15)*2, txx = (tid%15)*2;
  double acc[2][2][8];
  #pragma unroll
  for (int o=0;o<8;++o){
    double bv = bias[ocb+o];
    acc[0][0][o]=bv; acc[0][1][o]=bv; acc[1][0][o]=bv; acc[1][1][o]=bv;
  }
  for (int c0=0; c0<CIN; c0+=CIC){
    __syncthreads();
    // stage CIC x 32 x 32 as float4 granules (per-element guards at borders)
    for (int f4 = tid; f4 < CIC*256; f4 += 256){
      int ci = f4 >> 8; int rem = f4 & 255;
      int rr = rem >> 3; int c4 = rem & 7;
      int gy = ty0 + rr - 1, gx0 = tx0 + c4*4 - 1;
      float4 v = {0.f,0.f,0.f,0.f};
      if (gy >= 0 && gy < HW){
        const float* rowp = inb + (size_t)(c0+ci)*HW*HW + (size_t)gy*HW;
        float* vp = (float*)&v;
        #pragma unroll
        for (int e=0;e<4;++e){
          int gx = gx0 + e;
          if (gx >= 0 && gx < HW) vp[e] = rowp[gx];
        }
      }
      *(float4*)&s_in[ci][rr][c4*4] = v;
    }
    __syncthreads();
    if (active){
      for (int ci=0; ci<CIC; ++ci){
        double tap[4][4];
        #pragma unroll
        for (int rr=0;rr<4;++rr){
          float2 lo = *(const float2*)&s_in[ci][tyy+rr][txx];     // ds_read_b64
          float2 hi = *(const float2*)&s_in[ci][tyy+rr][txx+2];   // ds_read_b64
          tap[rr][0] = (double)lo.x; tap[rr][1] = (double)lo.y;
          tap[rr][2] = (double)hi.x; tap[rr][3] = (double)hi.y;
        }
        const double* wp = w + ((size_t)ocb*CIN + (c0+ci))*9;
        #pragma unroll
        for (int t=0;t<9;++t){
          const int ky = t/3, kx = t - ky*3;
          #pragma unroll
          for (int o=0;o<8;++o){
            double wv = wp[(size_t)o*CIN*9 + t];   // block-uniform -> scalar load
            acc[0][0][o] += tap[ky+0][kx+0]*wv;
            acc[0][1][o] += tap[ky+0][kx+1]*wv;
            acc[1][0][o] += tap[ky+1][kx+0]*wv;
            acc[1][1][o] += tap[ky+1][kx+1]*wv;
          }
        }
      }
    }
  }
  if (active){
    #pragma unroll
    for (int py=0;py<2;++py)
      #pragma unroll
      for (int px=0;px<2;++px){
        int gy = ty0+tyy+py, gx = tx0+txx+px;
        float* op = out + ((size_t)(b*CO+ocb)*HW + gy)*HW + gx;
        #pragma unroll
        for (int o=0;o<8;++o){
          double v = acc[py][px][o];
          op[(size_t)o*HW*HW] = (float)(v>0.0 ? v : 0.0);
        }
      }
  }
}

// ---------------- 2x2 max pool: (2,64,240,240) -> (2,64,120,120)  (exact)
__global__ __launch_bounds__(256) void k_maxpool(const float* __restrict__ in,
                                                 float* __restrict__ out){
  int i = blockIdx.x*256 + threadIdx.x;
  if (i >= 2*64*L) return;
  int bc = i / L; int p = i - bc*L; int y = p/W0, x = p - y*W0;
  const float* s = in + (size_t)bc*H1*W1;
  int yy = 2*y, xx = 2*x;
  out[i] = fmaxf(fmaxf(s[yy*W1+xx], s[yy*W1+xx+1]),
                 fmaxf(s[(yy+1)*W1+xx], s[(yy+1)*W1+xx+1]));
}

// ---------------- 1x1 conv 128->16 + LeakyReLU(0.2), fp64 accumulation
__global__ __launch_bounds__(256) void k_conv1x1(const float* __restrict__ in,
                                                 const double* __restrict__ wm,
                                                 const double* __restrict__ bm,
                                                 float* __restrict__ out){
  int i = blockIdx.x*256 + threadIdx.x;
  if (i >= 2*L) return;
  int b = i/L; int p = i - b*L;
  double a[16];
  #pragma unroll
  for (int o=0;o<16;++o) a[o] = bm[o];
  const float* src = in + (size_t)b*128*L + p;
  for (int ci=0; ci<128; ++ci){
    double v = (double)src[(size_t)ci*L];
    #pragma unroll
    for (int o=0;o<16;++o) a[o] += v * wm[o*128 + ci];  // uniform -> scalar load
  }
  float* dst = out + (size_t)b*16*L + p;
  #pragma unroll
  for (int o=0;o<16;++o){ double v=a[o]; dst[(size_t)o*L] = (float)(v>0.0 ? v : 0.2*v); }
}

// ---------------- im2col 3x3 pad1 + per-pixel L2 normalize (fp64), pixel-major.
// Block = 64 pixels: stage 4 feature rows in LDS (coalesced), serial per-pixel
// norm (same c,dy,dx ascending order -> bit-identical rn), lane-major col writes
// (coalesced f32/f16). Block x=225 (b=1 only) emits the 64 dup rows of key L-1.
__global__ __launch_bounds__(256) void k_patches(const float* __restrict__ fm,
                                                 _Float16* __restrict__ Tq16,
                                                 _Float16* __restrict__ Tk16,
                                                 float* __restrict__ Tq32,
                                                 float* __restrict__ Tk32){
  __shared__ float s[16][4][120];
  __shared__ double rns[64];
  int b  = blockIdx.y;
  int bx = blockIdx.x;
  bool pad = (bx == 225);
  if (pad && b == 0) return;
  int tid = threadIdx.x;
  int pix0 = bx*64;
  int y0 = pad ? 119 : (pix0/120);
  int ybase = y0 - 1;
  const float* src = fm + (size_t)b*16*L;
  for (int e = tid; e < 16*4*120; e += 256){
    int c = e/480; int r = (e/120)&3; int x = e%120;
    int gy = ybase + r;
    s[c][r][x] = (gy>=0 && gy<H0) ? src[c*L + gy*W0 + x] : 0.f;
  }
  __syncthreads();
  if (tid < 64){
    int p = pad ? (L-1) : (pix0 + tid);
    int y = p/W0, x = p - y*W0;
    double ss = 0.0;
    for (int c=0;c<16;++c){
      #pragma unroll
      for (int dy=0;dy<3;++dy){
        int r = y + dy - 1 - ybase;
        #pragma unroll
        for (int dx=0;dx<3;++dx){
          int gx = x + dx - 1;
          double v = (gx>=0 && gx<W0) ? (double)s[c][r][gx] : 0.0;
          ss += v*v;
        }
      }
    }
    rns[tid] = 1.0 / fmax(sqrt(ss), 1e-12);
  }
  __syncthreads();
  _Float16* T16 = (b==0) ? Tq16 : Tk16;
  float*    T32 = (b==0) ? Tq32 : Tk32;
  for (int e = tid; e < 64*CPAD; e += 256){
    int row = e/CPAD, col = e - row*CPAD;
    int p = pad ? (L-1) : (pix0 + row);
    int outrow = pad ? (L + row) : p;
    float f = 0.f;
    if (col < FDIM){
      int c = col/9; int rem = col - c*9; int dy = rem/3; int dx = rem - dy*3;
      int y = p/W0, x = p - y*W0;
      int r = y + dy - 1 - ybase;
      int gx = x + dx - 1;
      float v = (gx>=0 && gx<W0) ? s[c][r][gx] : 0.f;
      f = (float)((double)v * rns[row]);
    }
    T32[(size_t)outrow*CPAD + col] = f;
    T16[(size_t)outrow*CPAD + col] = (_Float16)f;
  }
}

// ---------------- PASS 1: f16 MFMA similarity scan -> per-(16-key-granule,query) max
__global__ __launch_bounds__(256) void k_simh(const _Float16* __restrict__ Tq,
                                              const _Float16* __restrict__ Tk,
                                              _Float16* __restrict__ cmaxh){
  __shared__ __align__(16) _Float16 skT[40*512];   // [kg 0..7][ks 0..4][cg][kk][8] = 40 KB
  int tid = threadIdx.x;
  int wid = tid >> 6, lane = tid & 63;
  int wk = wid & 1, wq = wid >> 1;
  int q0 = blockIdx.x * 96;
  int cg = lane >> 4;
  int qb = q0 + wq*48 + (lane & 15);
  half8 fB[3][5];
  #pragma unroll
  for (int bf=0; bf<3; ++bf)
    #pragma unroll
    for (int ks=0; ks<5; ++ks)
      fB[bf][ks] = *(const half8*)(Tq + (size_t)(qb + bf*16)*CPAD + ks*32 + cg*8);
  int ch0 = blockIdx.y * NCHB;
  for (int cc=0; cc<NCHB; ++cc){
    int chunk = ch0 + cc;
    if (chunk >= NCHT) break;
    int kbase = chunk * KC;
    __syncthreads();            // prior chunk's skT reads done
    #pragma unroll
    for (int it=0; it<10; ++it){
      int b1 = wid*10 + it;     // 1024-B block: kg=b1/5, ks=b1%5
      int kg = b1 / 5, ks = b1 % 5;
      const _Float16* g = Tk + (size_t)(kbase + kg*16 + (lane&15))*CPAD + ks*32 + cg*8;
      __builtin_amdgcn_global_load_lds((const __attribute__((address_space(1))) void*)g,
                                       (__attribute__((address_space(3))) void*)(skT + b1*512),
                                       16, 0, 0);
    }
    __syncthreads();            // staging complete
    f32x4 acc[4][3];
    #pragma unroll
    for (int kf=0;kf<4;++kf)
      #pragma unroll
      for (int bf=0;bf<3;++bf)
        acc[kf][bf] = (f32x4){0.f,0.f,0.f,0.f};
    #pragma unroll
    for (int ks=0; ks<5; ++ks){
      #pragma unroll
      for (int kf=0; kf<4; ++kf){
        half8 av = *(const half8*)(skT + ((size_t)((wk*4+kf)*5 + ks))*512 + lane*8);
        #pragma unroll
        for (int bf=0; bf<3; ++bf)
          acc[kf][bf] = __builtin_amdgcn_mfma_f32_16x16x32_f16(av, fB[bf][ks], acc[kf][bf], 0, 0, 0);
      }
    }
    // per-(16-key granule, query) max, biased-up f16 store
    #pragma unroll
    for (int kf=0; kf<4; ++kf){
      int gran = chunk*8 + wk*4 + kf;
      #pragma unroll
      for (int bf=0; bf<3; ++bf){
        f32x4 a = acc[kf][bf];
        float m = fmaxf(fmaxf(a.x, a.y), fmaxf(a.z, a.w));
        m = fmaxf(m, __shfl_xor(m, 16));
        m = fmaxf(m, __shfl_xor(m, 32));
        float mb = m * (m >= 0.f ? 1.0009765625f : 0.9990234375f);  // round-up bias
        if (lane < 16)
          cmaxh[(size_t)gran*L + q0 + wq*48 + bf*16 + lane] = (_Float16)mb;
      }
    }
  }
}

// ---------------- PASS 2a: wave-per-query gmax + ascending flagged list.
__global__ __launch_bounds__(256) void k_flag(const _Float16* __restrict__ cmaxh,
                                              unsigned short* __restrict__ list,
                                              int* __restrict__ nf,
                                              float* __restrict__ thrv){
  int q    = blockIdx.x*4 + (threadIdx.x >> 6);
  int lane = threadIdx.x & 63;
  if (q >= L) return;
  float v[15];
  #pragma unroll
  for (int j=0;j<15;++j){
    int g = j*64 + lane;
    v[j] = (g < NGRAN) ? (float)cmaxh[(size_t)g*L + q] : -1e30f;
  }
  float m = -1e30f;
  #pragma unroll
  for (int j=0;j<15;++j) m = fmaxf(m, v[j]);
  #pragma unroll
  for (int d=32; d>=1; d>>=1) m = fmaxf(m, __shfl_xor(m, d));
  float thr = m - MARGIN;
  unsigned short* lst = list + (size_t)q*NLIST;
  int base = 0;
  #pragma unroll
  for (int j=0;j<15;++j){
    bool f = v[j] >= thr;
    unsigned long long mask = __ballot(f);
    if (f){
      int pos = base + __popcll(mask & ((1ull<<lane)-1ull));
      if (pos < NLIST) lst[pos] = (unsigned short)(j*64 + lane);
    }
    base += __popcll(mask);
  }
  if (lane == 0){ nf[q] = base; thrv[q] = thr; }
}

// ---------------- PASS 2b: fp64 rescore of flagged granules, one wave per query.
__global__ __launch_bounds__(64) void k_rescore3(const float* __restrict__ Tq32,
                                                 const float* __restrict__ Tk32,
                                                 const unsigned short* __restrict__ list,
                                                 const int* __restrict__ nf,
                                                 const float* __restrict__ thrv,
                                                 const _Float16* __restrict__ cmaxh,
                                                 float* __restrict__ out){
  int q = blockIdx.x, lane = threadIdx.x;
  int slot = lane & 15, quarter = lane >> 4;
  const float* qp = Tq32 + (size_t)q*CPAD + quarter*36;
  double q64[36];
  #pragma unroll
  for (int c=0;c<36;++c) q64[c] = (double)qp[c];
  int n = nf[q];
  float thr = thrv[q];
  double best = -1e300; int bi = 0x7fffffff;

  auto proc = [&](int g){
    int key = g*16 + slot;                    // key < LPAD always
    const float* kr = Tk32 + (size_t)key*CPAD + quarter*36;
    double s = 0.0;
    #pragma unroll
    for (int c=0;c<36;++c) s += q64[c]*(double)kr[c];
    s += __shfl_xor(s, 16);
    s += __shfl_xor(s, 32);                   // full dot for this slot's key, all lanes
    if (key < L && s > best){ best = s; bi = key; }  // dup keys (>=L) excluded
  };

  if (n <= NLIST){
    const unsigned short* lst = list + (size_t)q*NLIST;
    for (int it=0; it<n; ++it) proc(lst[it]);
  } else {
    for (int g=0; g<NGRAN; ++g)               // rare fallback (mass ties)
      if ((float)cmaxh[(size_t)g*L + q] >= thr) proc(g);
  }
  // cross-slot reduce with min-index tie-break (quarter lanes mirror slot state)
  #pragma unroll
  for (int d=1; d<16; d<<=1){
    double v2 = __shfl_xor(best, d);
    int    i2 = __shfl_xor(bi, d);
    if (v2 > best || (v2 == best && i2 < bi)){ best = v2; bi = i2; }
  }
  if (lane == 0){
    out[q]     = (float)best;     // rel
    out[L + q] = (float)bi;       // idx (exact in f32: < 2^24)
  }
}

extern "C" void kernel_launch(void* const* d_in, const int* in_sizes, int n_in,
                              void* d_out, int out_size, void* d_ws, size_t ws_size,
                              hipStream_t stream){
  const float* query = (const float*)d_in[0];
  const float* key   = (const float*)d_in[1];
  const float* w1 = (const float*)d_in[2];
  const float* b1 = (const float*)d_in[3];
  const float* w2 = (const float*)d_in[4];
  const float* b2 = (const float*)d_in[5];
  const float* w3 = (const float*)d_in[6];
  const float* b3 = (const float*)d_in[7];
  const float* wm = (const float*)d_in[8];
  const float* bm = (const float*)d_in[9];
  float* out = (float*)d_out;

  // ---- workspace layout ----
  double* wd = (double*)d_ws;   // 114640 doubles of converted weights
  double* wd1 = wd;            // 1728
  double* bd1 = wd + 1728;     // 64
  double* wd2 = wd + 1792;     // 36864
  double* bd2 = wd + 38656;    // 64
  double* wd3 = wd + 38720;    // 73728
  double* bd3 = wd + 112448;   // 128
  double* wdm = wd + 112576;   // 2048
  double* bdm = wd + 114624;   // 16
  float* fbase = (float*)d_ws + 230400;
  float* nq = fbase;                            //   86400
  float* up = nq + 86400;                       //  345600
  float* A  = up + 345600;                      // 7372800  (conv1 out)
  float* Bf = A  + 7372800;                     // 7372800  (conv2 out)
  float* C  = A;                                // 1843200  (pool out; A dead after conv2)
  float* D  = A + 1843200;                      // 3686400  (conv3 out)
  float* FM = Bf + 7372800 - 460800;            //  460800  (1x1 out; Bf tail = A+14,284,800)
  // pixel-major sim operands overlay A/Bf-head (dead by k_patches time):
  _Float16* Tq16 = (_Float16*)A;                          // 2,304,000 h = 1,152,000 fl
  _Float16* Tk16 = (_Float16*)(A + 1152000);              // 2,314,240 h = 1,157,120 fl
  float*    Tq32 = A + 2309120;                           // 2,304,000 fl
  float*    Tk32 = Tq32 + 2304000;                        // 2,314,240 fl (ends A+6,927,360)
  _Float16* cmaxh = (_Float16*)(A + 6927360);             // 904*14400 h = 6,508,800 fl
  unsigned short* list = (unsigned short*)(A + 13436160); // 14400*32 u16 = 230,400 fl
  int*   nfl  = (int*)(A + 13666560);                     // 14,400 fl
  float* thrv = A + 13680960;                             // 14,400 fl (ends A+13,695,360 < FM)

  k_cvt_all<<<(114640+255)/256, 256, 0, stream>>>(w1,b1,w2,b2,w3,b3,wm,bm, wd);

  k_prep   <<<(2*3*L + 255)/256, 256, 0, stream>>>(query, key, nq);
  k_bicubic<<<(2*3*H1*W1 + 255)/256, 256, 0, stream>>>(nq, up);
  k_conv3x3<3,3,240><<<dim3(64,8,2), 256, 0, stream>>>(up, wd1, bd1, A, 64);
  k_conv3x3<64,8,240><<<dim3(64,8,2), 256, 0, stream>>>(A, wd2, bd2, Bf, 64);
  k_maxpool<<<(2*64*L + 255)/256, 256, 0, stream>>>(Bf, C);
  k_conv3x3<64,8,120><<<dim3(16,16,2), 256, 0, stream>>>(C, wd3, bd3, D, 128);
  k_conv1x1<<<(2*L + 255)/256, 256, 0, stream>>>(D, wdm, bdm, FM);
  k_patches<<<dim3(226,2), 256, 0, stream>>>(FM, Tq16, Tk16, Tq32, Tk32);
  k_simh   <<<dim3(150, 15), 256, 0, stream>>>(Tq16, Tk16, cmaxh);
  k_flag   <<<(L + 3)/4, 256, 0, stream>>>(cmaxh, list, nfl, thrv);
  k_rescore3<<<L, 64, 0, stream>>>(Tq32, Tk32, list, nfl, thrv, cmaxh, out);
}